// Round 8
// baseline (669.465 us; speedup 1.0000x reference)
//
#include <hip/hip_runtime.h>

// LQR KKT solve via backward Riccati recursion + forward rollout.
// T=128, n_state=16, n_ctrl=8, n_all=24.
// Base: the PROVEN round-7 kernel (356us, absmax 0.0039; 2x2-block GJ,
// float4 LDS dots, padded strides).
// SINGLE delta this round: 256 threads (4 waves) -> 64 threads (1 wave).
// Each lane runs the work-units of its 4 former siblings (u = l + 64*r)
// with per-unit code identical to R7. All __syncthreads() kept: for a
// single-wave workgroup they lower to waitcnt-only fences (s_barrier
// elided), removing the ~400-600 cy/phase 4-wave rendezvous that R7's
// profile showed dominates (740 cy/phase avg vs ~150-400 cy of content).
// Phase read/write sets are disjoint (ping-pong Aug/P_sh/p_sh/Csh), so
// intra-lane serialization of units is order-safe.
// NOTE: Gu dual-write (R3/R4/R5) remains banned (empirically convicted).
// mu_t = P_t x_t + p_t (stable), not the costate recursion.

constexpr int T  = 128;
constexpr int NA = 24;

// 16-element dot product via 4x float4 LDS reads. Both ptrs 16B-aligned.
__device__ __forceinline__ float dot16f4(const float* a, const float* b, float s) {
    const float4* a4 = (const float4*)a;
    const float4* b4 = (const float4*)b;
#pragma unroll
    for (int q = 0; q < 4; ++q) {
        float4 x = a4[q], y = b4[q];
        s = fmaf(x.x, y.x, s); s = fmaf(x.y, y.y, s);
        s = fmaf(x.z, y.z, s); s = fmaf(x.w, y.w, s);
    }
    return s;
}

__global__ __launch_bounds__(64, 1)
void lqr_solve(const float* __restrict__ gA,
               const float* __restrict__ gB,
               const float* __restrict__ gx0,
               const float* __restrict__ gC,
               const float* __restrict__ gc,
               float* __restrict__ out,
               float* __restrict__ Pws,   // [T*256] scratch: P_t row-major
               float* __restrict__ pws)   // [T*16]  scratch: p_t
{
    __shared__ __align__(16) float A_sh[16][16];   // A row-major
    __shared__ __align__(16) float At_sh[16][16];  // A^T row-major
    __shared__ __align__(16) float B_sh[16][8];
    __shared__ __align__(16) float Bt_sh[8][16];
    __shared__ __align__(16) float P_sh[2][16][20]; // padded stride 20
    __shared__ __align__(16) float p_sh[2][16];
    __shared__ __align__(16) float Wt[16][20];     // Wt[j][k] = (P'A)[k][j]
    __shared__ __align__(16) float Vt[8][20];      // Vt[j][k] = (P'B)[k][j]
    __shared__ __align__(16) float Gu[16][8];      // S + A^T P' B
    __shared__ __align__(16) float Aug[2][8][27];  // ping-pong [H|G|rhs]
    __shared__ __align__(16) float Kall[T][8][16];
    __shared__ __align__(16) float kall[T][8];
    __shared__ __align__(16) float c_sh[T][NA];
    __shared__ __align__(16) float z_sh[T][NA];    // x=[0:16), u=[16:24)
    __shared__ __align__(16) float Csh[2][24][25]; // double-buffered C_t

    const int l = threadIdx.x;

    // ---- init: load A, B, c, C_{T-1}; P_T = 0, p_T = 0 ----
#pragma unroll
    for (int r = 0; r < 4; ++r) {
        const int u = l + 64 * r;
        const int i = u >> 4, j = u & 15;
        const float v = gA[u];
        A_sh[i][j] = v; At_sh[j][i] = v;
        P_sh[0][i][j] = 0.0f;
        if (j < 4) P_sh[0][i][16 + j] = 0.0f;  // zero the pad too
    }
#pragma unroll
    for (int r = 0; r < 2; ++r) {
        const int u = l + 64 * r;
        const int i = u >> 3, j = u & 7;
        const float v = gB[u];
        B_sh[i][j] = v; Bt_sh[j][i] = v;
    }
    if (l < 16) p_sh[0][l] = 0.0f;
    for (int idx = l; idx < T * NA; idx += 64) c_sh[idx / NA][idx % NA] = gc[idx];
    for (int idx = l; idx < 576; idx += 64)
        Csh[0][idx / 24][idx % 24] = gC[(T - 1) * 576 + idx];
    __syncthreads();

    // ---- backward Riccati pass ----
    int pb = 0; // P_sh buffer holding P_{t+1}
    for (int t = T - 1; t >= 0; --t) {
        const int cb = (T - 1 - t) & 1; // Csh buffer holding C_t

        // register-prefetch C_{t-1} (committed to Csh[cb^1] in phase 5)
        float pf[9];
        if (t > 0) {
            const float* src = gC + (size_t)(t - 1) * 576;
#pragma unroll
            for (int r = 0; r < 9; ++r) pf[r] = src[l + 64 * r];
        }

        // phase 1+2: Wt = (P'A)^T, Vt = (P'B)^T  (float4 row reads)
#pragma unroll
        for (int r = 0; r < 4; ++r) {
            const int u = l + 64 * r;
            const int j = u >> 4, k = u & 15;      // k == l&15 for all r (CSE)
            Wt[j][k] = dot16f4(&P_sh[pb][k][0], &At_sh[j][0], 0.0f);
        }
#pragma unroll
        for (int r = 0; r < 2; ++r) {
            const int u = l + 64 * r;
            const int jb = u >> 4, k = u & 15;
            Vt[jb][k] = dot16f4(&P_sh[pb][k][0], &Bt_sh[jb][0], 0.0f);
        }
        __syncthreads();

        // phase 3: Aug = [H | G | rhs] (8x25) and Gu = S + A^T V (16x8)
#pragma unroll
        for (int r = 0; r < 4; ++r) {
            const int u = l + 64 * r;
            if (u < 200) {
                const int i = u / 25, j = u % 25;
                float s;
                if (j < 8) {                    // H = R + B^T P' B
                    s = dot16f4(&Bt_sh[i][0], &Vt[j][0], Csh[cb][16 + i][16 + j]);
                } else if (j < 24) {            // G = S^t + B^T P' A
                    const int jj = j - 8;
                    s = dot16f4(&Bt_sh[i][0], &Wt[jj][0], Csh[cb][16 + i][jj]);
                } else {                        // rhs = r + B^T p'
                    s = dot16f4(&Bt_sh[i][0], &p_sh[pb][0], c_sh[t][16 + i]);
                }
                Aug[0][i][j] = s;
            }
        }
#pragma unroll
        for (int r = 0; r < 2; ++r) {
            const int u = l + 64 * r;
            const int i = u >> 3, j = u & 7;
            Gu[i][j] = dot16f4(&At_sh[i][0], &Vt[j][0], Csh[cb][i][16 + j]);
        }
        __syncthreads();

        // phase 4: Gauss-Jordan, 2x2 block pivots (4 rounds, 1 fence each).
        // Rounds kk=0,2,4,6 read rb=0,1,0,1 / write wb -> result in Aug[0].
        #pragma unroll
        for (int kk = 0; kk < 8; kk += 2) {
            const int rb = (kk >> 1) & 1, wb = rb ^ 1;
            const float a  = Aug[rb][kk][kk],     b = Aug[rb][kk][kk + 1];
            const float c2 = Aug[rb][kk + 1][kk], d = Aug[rb][kk + 1][kk + 1];
            const float rdet = 1.0f / fmaf(a, d, -b * c2);
#pragma unroll
            for (int r = 0; r < 4; ++r) {
                const int u = l + 64 * r;
                if (u < 200) {
                    const int i = u / 25, j = u % 25;
                    const float pk0 = Aug[rb][kk][j], pk1 = Aug[rb][kk + 1][j];
                    const float w0 = (d * pk0 - b * pk1) * rdet;
                    const float w1 = (a * pk1 - c2 * pk0) * rdet;
                    float v;
                    if (i == kk)          v = w0;
                    else if (i == kk + 1) v = w1;
                    else v = fmaf(-Aug[rb][i][kk], w0,
                                  fmaf(-Aug[rb][i][kk + 1], w1, Aug[rb][i][j]));
                    Aug[wb][i][j] = v;
                }
            }
            __syncthreads();
        }
        // Aug[0] = [I | K | k],  K = H^-1 G,  k = H^-1 rhs

        // phase 5: P_t = Q + A^T W - Gu K ; p_t = q + A^T p' - Gu k ; save K,k
#pragma unroll
        for (int r = 0; r < 4; ++r) {
            const int u = l + 64 * r;
            const int i = u >> 4, j = u & 15;      // j == l&15 for all r (CSE)
            float s = dot16f4(&At_sh[i][0], &Wt[j][0], Csh[cb][i][j]);
            float s2 = 0.f;
            const float4 g0 = *(const float4*)&Gu[i][0];
            const float4 g1 = *(const float4*)&Gu[i][4];
            s2 = fmaf(g0.x, Aug[0][0][8 + j], s2);
            s2 = fmaf(g0.y, Aug[0][1][8 + j], s2);
            s2 = fmaf(g0.z, Aug[0][2][8 + j], s2);
            s2 = fmaf(g0.w, Aug[0][3][8 + j], s2);
            s2 = fmaf(g1.x, Aug[0][4][8 + j], s2);
            s2 = fmaf(g1.y, Aug[0][5][8 + j], s2);
            s2 = fmaf(g1.z, Aug[0][6][8 + j], s2);
            s2 = fmaf(g1.w, Aug[0][7][8 + j], s2);
            const float v = s - s2;
            P_sh[pb ^ 1][i][j] = v;
            Pws[t * 256 + u] = v;   // for mu_t = P_t x_t + p_t later
        }
#pragma unroll
        for (int r = 0; r < 2; ++r) {
            const int u = l + 64 * r;
            const int i = u >> 4, j = u & 15;
            Kall[t][i][j] = Aug[0][i][8 + j];
        }
        if (l < 8) kall[t][l] = Aug[0][l][24];
        if (l < 16) {
            float s = dot16f4(&At_sh[l][0], &p_sh[pb][0], c_sh[t][l]);
            float s2 = 0.f;
            #pragma unroll
            for (int q = 0; q < 8; ++q) s2 = fmaf(Gu[l][q], Aug[0][q][24], s2);
            const float v = s - s2;
            p_sh[pb ^ 1][l] = v;
            pws[t * 16 + l] = v;
        }
        if (t > 0) { // commit prefetched C_{t-1}
#pragma unroll
            for (int r = 0; r < 9; ++r) {
                const int u = l + 64 * r;
                Csh[cb ^ 1][u / 24][u % 24] = pf[r];
            }
        }
        __syncthreads();
        pb ^= 1;
    }

    // drain our own global stores (Pws/pws) before re-reading them below:
    // same-wave global store->load to the same address is unordered w/o this.
    asm volatile("s_waitcnt vmcnt(0)" ::: "memory");

    // ---- forward rollout + mu ----
    if (l < 16) z_sh[0][l] = gx0[l];
    __syncthreads();
    for (int t = 0; t < T; ++t) {
        if (l < 8) {                         // u_t = -(K_t x_t + k_t)
            float s = dot16f4(&Kall[t][l][0], &z_sh[t][0], kall[t][l]);
            z_sh[t][16 + l] = -s;
        }
        if (l >= 32 && l < 48) {             // mu_t = +/- (P_t x_t + p_t)
            const int i = l - 32;
            float s = pws[t * 16 + i];
            const float4* Pr = (const float4*)(Pws + t * 256 + i * 16);
            const float4* zr = (const float4*)&z_sh[t][0];
            #pragma unroll
            for (int q = 0; q < 4; ++q) {
                float4 p = Pr[q], z = zr[q];
                s = fmaf(p.x, z.x, s); s = fmaf(p.y, z.y, s);
                s = fmaf(p.z, z.z, s); s = fmaf(p.w, z.w, s);
            }
            if (t == 0) s = -s;              // mu_0 = -(P_0 x_0 + p_0)
            out[T * NA + t * 16 + i] = s;
        }
        __syncthreads();
        if (t < T - 1 && l < 16) {           // x_{t+1} = A x_t + B u_t
            float s = dot16f4(&A_sh[l][0], &z_sh[t][0], 0.0f);
            const float4 b0 = *(const float4*)&B_sh[l][0];
            const float4 b1 = *(const float4*)&B_sh[l][4];
            const float4 u0 = *(const float4*)&z_sh[t][16];
            const float4 u1 = *(const float4*)&z_sh[t][20];
            s = fmaf(b0.x, u0.x, s); s = fmaf(b0.y, u0.y, s);
            s = fmaf(b0.z, u0.z, s); s = fmaf(b0.w, u0.w, s);
            s = fmaf(b1.x, u1.x, s); s = fmaf(b1.y, u1.y, s);
            s = fmaf(b1.z, u1.z, s); s = fmaf(b1.w, u1.w, s);
            z_sh[t + 1][l] = s;
        }
        __syncthreads();
    }

    // ---- write z ----
    for (int idx = l; idx < T * NA; idx += 64)
        out[idx] = z_sh[idx / 24][idx % 24];
}

extern "C" void kernel_launch(void* const* d_in, const int* in_sizes, int n_in,
                              void* d_out, int out_size, void* d_ws, size_t ws_size,
                              hipStream_t stream) {
    const float* gA  = (const float*)d_in[0];
    const float* gB  = (const float*)d_in[1];
    const float* gx0 = (const float*)d_in[2];
    const float* gC  = (const float*)d_in[3];
    const float* gc  = (const float*)d_in[4];
    float* out = (float*)d_out;
    float* Pws = (float*)d_ws;           // T*256 floats
    float* pws = Pws + T * 256;          // T*16 floats  (total ~139 KB << ws)
    lqr_solve<<<dim3(1), dim3(64), 0, stream>>>(gA, gB, gx0, gC, gc, out, Pws, pws);
}

// Round 9
// 366.505 us; speedup vs baseline: 1.8266x; 1.8266x over previous
//
#include <hip/hip_runtime.h>

// LQR KKT solve via backward Riccati recursion + forward rollout.
// T=128, n_state=16, n_ctrl=8, n_all=24. Single block, 256 threads (4 waves;
// R8 proved 1 wave is 1.76x WORSE -- phases are LDS-pipe-bound, not
// barrier-bound). Base: proven R7 (356us). Three deltas, all cutting DS-pipe
// traffic / phase count:
//  (1) reg-cached invariant operand rows (At/Bt/B, fixed lane->row mapping)
//  (2) GJ: 2 rounds of 4x4 block pivots (2x2-Schur per lane; H SPD >= I so
//      all nested Schur complements >= I, dets >= 1 -> pivot-free safe)
//  (3) forward: 1 phase/step via F_t = A - B K_t, d_t = -B k_t precomputed
//      in backward phase-5 (reuses K column regs), stored in global ws.
// Gu dual-write (R3/R4/R5) remains banned. mu_t = P_t x_t + p_t (stable).
// d_ws layout: Pws[T*256] | pws[T*16] | Fws[T*256] | dws[T*16] = 272 KB.

constexpr int T  = 128;
constexpr int NA = 24;

// 16-elem dot: LDS float4 stream  x  register-resident row (static idx).
__device__ __forceinline__ float dot16r(const float* lds, const float* r, float s) {
    const float4* a4 = (const float4*)lds;
#pragma unroll
    for (int q = 0; q < 4; ++q) {
        float4 x = a4[q];
        s = fmaf(x.x, r[4 * q + 0], s); s = fmaf(x.y, r[4 * q + 1], s);
        s = fmaf(x.z, r[4 * q + 2], s); s = fmaf(x.w, r[4 * q + 3], s);
    }
    return s;
}
// 16-elem dot: both operands LDS float4 (as in R7).
__device__ __forceinline__ float dot16f4(const float* a, const float* b, float s) {
    const float4* a4 = (const float4*)a;
    const float4* b4 = (const float4*)b;
#pragma unroll
    for (int q = 0; q < 4; ++q) {
        float4 x = a4[q], y = b4[q];
        s = fmaf(x.x, y.x, s); s = fmaf(x.y, y.y, s);
        s = fmaf(x.z, y.z, s); s = fmaf(x.w, y.w, s);
    }
    return s;
}

__global__ __launch_bounds__(256, 1)
void lqr_solve(const float* __restrict__ gA,
               const float* __restrict__ gB,
               const float* __restrict__ gx0,
               const float* __restrict__ gC,
               const float* __restrict__ gc,
               float* __restrict__ out,
               float* __restrict__ Pws,   // [T*256] P_t row-major
               float* __restrict__ pws,   // [T*16]  p_t
               float* __restrict__ Fws,   // [T*256] F_t = A - B K_t
               float* __restrict__ dws)   // [T*16]  d_t = -B k_t
{
    __shared__ __align__(16) float A_sh[16][16];
    __shared__ __align__(16) float At_sh[16][16];
    __shared__ __align__(16) float B_sh[16][8];
    __shared__ __align__(16) float Bt_sh[8][16];
    __shared__ __align__(16) float P_sh[2][16][20];
    __shared__ __align__(16) float p_sh[2][16];
    __shared__ __align__(16) float Wt[16][20];
    __shared__ __align__(16) float Vt[8][20];
    __shared__ __align__(16) float Gu[16][8];
    __shared__ __align__(16) float Aug[2][8][27];
    __shared__ __align__(16) float Kall[T][8][16];
    __shared__ __align__(16) float kall[T][8];
    __shared__ __align__(16) float c_sh[T][NA];
    __shared__ __align__(16) float z_sh[T][NA];
    __shared__ __align__(16) float Csh[2][24][25];

    const int tid = threadIdx.x;

    // ---- init staging (identical to R7) ----
    {
        const int i = tid >> 4, j = tid & 15;
        const float v = gA[tid];
        A_sh[i][j] = v; At_sh[j][i] = v;
        P_sh[0][i][j] = 0.0f;
        if (j < 4) P_sh[0][i][16 + j] = 0.0f;
    }
    if (tid < 128) {
        const int i = tid >> 3, j = tid & 7;
        const float v = gB[tid];
        B_sh[i][j] = v; Bt_sh[j][i] = v;
    }
    if (tid < 16) p_sh[0][tid] = 0.0f;
    for (int idx = tid; idx < T * NA; idx += 256) c_sh[idx / NA][idx % NA] = gc[idx];
    for (int idx = tid; idx < 576; idx += 256)
        Csh[0][idx / 24][idx % 24] = gC[(T - 1) * 576 + idx];
    __syncthreads();

    // ---- per-lane register caches of invariant rows ----
    float atr[16], btr_e[16], btr3[16], atr2[16], brow[8], browp[8];
    {
        const int rA  = tid >> 4;          // At/B row: E-phase, phase-5, F
        const int rBe = (tid >> 4) & 7;    // Bt row: E-phase Vt part
        const int rB3 = (tid / 25) & 7;    // Bt row: phase-3
        const int rA2 = (tid >> 3) & 15;   // At row: Gu
        const int rBp = tid & 15;          // B row: d_t (lanes<16)
#pragma unroll
        for (int q = 0; q < 4; ++q) {
            float4 v;
            v = *(const float4*)&At_sh[rA][4 * q];
            atr[4*q]=v.x; atr[4*q+1]=v.y; atr[4*q+2]=v.z; atr[4*q+3]=v.w;
            v = *(const float4*)&Bt_sh[rBe][4 * q];
            btr_e[4*q]=v.x; btr_e[4*q+1]=v.y; btr_e[4*q+2]=v.z; btr_e[4*q+3]=v.w;
            v = *(const float4*)&Bt_sh[rB3][4 * q];
            btr3[4*q]=v.x; btr3[4*q+1]=v.y; btr3[4*q+2]=v.z; btr3[4*q+3]=v.w;
            v = *(const float4*)&At_sh[rA2][4 * q];
            atr2[4*q]=v.x; atr2[4*q+1]=v.y; atr2[4*q+2]=v.z; atr2[4*q+3]=v.w;
        }
#pragma unroll
        for (int q = 0; q < 2; ++q) {
            float4 v;
            v = *(const float4*)&B_sh[rA][4 * q];
            brow[4*q]=v.x; brow[4*q+1]=v.y; brow[4*q+2]=v.z; brow[4*q+3]=v.w;
            v = *(const float4*)&B_sh[rBp][4 * q];
            browp[4*q]=v.x; browp[4*q+1]=v.y; browp[4*q+2]=v.z; browp[4*q+3]=v.w;
        }
    }

    // ---- backward Riccati ----
    int pb = 0;
    for (int t = T - 1; t >= 0; --t) {
        const int cb = (T - 1 - t) & 1;

        float pf0 = 0.f, pf1 = 0.f, pf2 = 0.f;
        if (t > 0) {
            const float* src = gC + (size_t)(t - 1) * 576;
            pf0 = src[tid];
            pf1 = src[tid + 256];
            if (tid < 64) pf2 = src[tid + 512];
        }

        // phase 1: Wt = (P'A)^T, Vt = (P'B)^T  (P' from LDS, A/B from regs)
        {
            const int j = tid >> 4, k = tid & 15;
            Wt[j][k] = dot16r(&P_sh[pb][k][0], atr, 0.0f);
            if (tid < 128) {
                Vt[j][k] = dot16r(&P_sh[pb][k][0], btr_e, 0.0f);
            }
        }
        __syncthreads();

        // phase 2: Aug = [H | G | rhs] and Gu = S + A^T P' B
        if (tid < 200) {
            const int i = tid / 25, j = tid % 25;
            float s;
            if (j < 8) {
                s = dot16r(&Vt[j][0], btr3, Csh[cb][16 + i][16 + j]);
            } else if (j < 24) {
                const int jj = j - 8;
                s = dot16r(&Wt[jj][0], btr3, Csh[cb][16 + i][jj]);
            } else {
                s = dot16r(&p_sh[pb][0], btr3, c_sh[t][16 + i]);
            }
            Aug[0][i][j] = s;
        }
        if (tid < 128) {
            const int i = tid >> 3, j = tid & 7;
            Gu[i][j] = dot16r(&Vt[j][0], atr2, Csh[cb][i][16 + j]);
        }
        __syncthreads();

        // phase 3+4: Gauss-Jordan, TWO rounds of 4x4 block pivots.
        // kk=0 reads Aug[0]->writes Aug[1]; kk=4 reads Aug[1]->writes Aug[0].
#pragma unroll
        for (int kk = 0; kk < 8; kk += 4) {
            const int rb = (kk >> 2) & 1, wb = rb ^ 1;
            // pivot block (broadcast reads; same addrs across all lanes)
            const float m00=Aug[rb][kk+0][kk+0], m01=Aug[rb][kk+0][kk+1],
                        m02=Aug[rb][kk+0][kk+2], m03=Aug[rb][kk+0][kk+3];
            const float m10=Aug[rb][kk+1][kk+0], m11=Aug[rb][kk+1][kk+1],
                        m12=Aug[rb][kk+1][kk+2], m13=Aug[rb][kk+1][kk+3];
            const float m20=Aug[rb][kk+2][kk+0], m21=Aug[rb][kk+2][kk+1],
                        m22=Aug[rb][kk+2][kk+2], m23=Aug[rb][kk+2][kk+3];
            const float m30=Aug[rb][kk+3][kk+0], m31=Aug[rb][kk+3][kk+1],
                        m32=Aug[rb][kk+3][kk+2], m33=Aug[rb][kk+3][kk+3];
            // a^-1 (2x2, det >= 1)
            const float ra   = 1.0f / fmaf(m00, m11, -m01 * m10);
            const float ai00 =  m11 * ra, ai01 = -m01 * ra;
            const float ai10 = -m10 * ra, ai11 =  m00 * ra;
            // aib = a^-1 b
            const float aib00 = ai00*m02 + ai01*m12, aib01 = ai00*m03 + ai01*m13;
            const float aib10 = ai10*m02 + ai11*m12, aib11 = ai10*m03 + ai11*m13;
            // S = d - c aib (SPD >= I)
            const float s00 = m22 - (m20*aib00 + m21*aib10);
            const float s01 = m23 - (m20*aib01 + m21*aib11);
            const float s10 = m32 - (m30*aib00 + m31*aib10);
            const float s11 = m33 - (m30*aib01 + m31*aib11);
            const float rs   = 1.0f / fmaf(s00, s11, -s01 * s10);
            const float si00 =  s11 * rs, si01 = -s01 * rs;
            const float si10 = -s10 * rs, si11 =  s00 * rs;
            if (tid < 200) {
                const int i = tid / 25, j = tid % 25;
                const float pt0 = Aug[rb][kk+0][j], pt1 = Aug[rb][kk+1][j];
                const float pq0 = Aug[rb][kk+2][j], pq1 = Aug[rb][kk+3][j];
                // w = M^-1 p  via block elimination
                const float y0 = ai00*pt0 + ai01*pt1;
                const float y1 = ai10*pt0 + ai11*pt1;
                const float z0 = pq0 - (m20*y0 + m21*y1);
                const float z1 = pq1 - (m30*y0 + m31*y1);
                const float w2 = si00*z0 + si01*z1;
                const float w3 = si10*z0 + si11*z1;
                const float w0 = y0 - (aib00*w2 + aib01*w3);
                const float w1 = y1 - (aib10*w2 + aib11*w3);
                float v;
                if      (i == kk + 0) v = w0;
                else if (i == kk + 1) v = w1;
                else if (i == kk + 2) v = w2;
                else if (i == kk + 3) v = w3;
                else {
                    v = Aug[rb][i][j];
                    v = fmaf(-Aug[rb][i][kk+0], w0, v);
                    v = fmaf(-Aug[rb][i][kk+1], w1, v);
                    v = fmaf(-Aug[rb][i][kk+2], w2, v);
                    v = fmaf(-Aug[rb][i][kk+3], w3, v);
                }
                Aug[wb][i][j] = v;
                if (kk == 4 && j >= 8) {      // final round: export K,k
                    if (j < 24) Kall[t][i][j - 8] = v;
                    else        kall[t][i] = v;
                }
            }
            __syncthreads();
        }
        // Aug[0] = [I | K | k]

        // phase 5: P_t, p_t, F_t, d_t
        {
            const int i = tid >> 4, j = tid & 15;
            float kc[8];
#pragma unroll
            for (int y = 0; y < 8; ++y) kc[y] = Aug[0][y][8 + j];
            float s = dot16r(&Wt[j][0], atr, Csh[cb][i][j]);
            float s2 = 0.f;
            const float4 g0 = *(const float4*)&Gu[i][0];
            const float4 g1 = *(const float4*)&Gu[i][4];
            s2 = fmaf(g0.x, kc[0], s2); s2 = fmaf(g0.y, kc[1], s2);
            s2 = fmaf(g0.z, kc[2], s2); s2 = fmaf(g0.w, kc[3], s2);
            s2 = fmaf(g1.x, kc[4], s2); s2 = fmaf(g1.y, kc[5], s2);
            s2 = fmaf(g1.z, kc[6], s2); s2 = fmaf(g1.w, kc[7], s2);
            const float v = s - s2;
            P_sh[pb ^ 1][i][j] = v;
            Pws[t * 256 + tid] = v;
            // F_ij = A_ij - sum_y B_iy K_yj   (brow = B row i, kc = K col j)
            float fa = 0.f;
#pragma unroll
            for (int y = 0; y < 8; ++y) fa = fmaf(brow[y], kc[y], fa);
            Fws[t * 256 + tid] = A_sh[i][j] - fa;
        }
        if (tid < 16) {
            float kk8[8];
#pragma unroll
            for (int q = 0; q < 8; ++q) kk8[q] = Aug[0][q][24];
            float s = dot16f4(&At_sh[tid][0], &p_sh[pb][0], c_sh[t][tid]);
            float s2 = 0.f;
#pragma unroll
            for (int q = 0; q < 8; ++q) s2 = fmaf(Gu[tid][q], kk8[q], s2);
            const float v = s - s2;
            p_sh[pb ^ 1][tid] = v;
            pws[t * 16 + tid] = v;
            // d_i = -sum_y B_iy k_y   (browp = B row tid)
            float da = 0.f;
#pragma unroll
            for (int y = 0; y < 8; ++y) da = fmaf(browp[y], kk8[y], da);
            dws[t * 16 + tid] = -da;
        }
        if (t > 0) {
            Csh[cb ^ 1][tid / 24][tid % 24] = pf0;
            Csh[cb ^ 1][(tid + 256) / 24][(tid + 256) % 24] = pf1;
            if (tid < 64) Csh[cb ^ 1][(tid + 512) / 24][(tid + 512) % 24] = pf2;
        }
        __syncthreads();
        pb ^= 1;
    }

    // drain Pws/pws/Fws/dws stores before re-reading (same-wave global
    // store->load is unordered without this; barrier also drains, belt+braces)
    asm volatile("s_waitcnt vmcnt(0)" ::: "memory");

    // ---- forward rollout: ONE phase per step ----
    if (tid < 16) z_sh[0][tid] = gx0[tid];
    float fcur[16], dcur = 0.f, prow[16], pcur = 0.f;
    if (tid < 16) {
#pragma unroll
        for (int q = 0; q < 4; ++q) {
            float4 v = *(const float4*)&Fws[tid * 16 + 4 * q];
            fcur[4*q]=v.x; fcur[4*q+1]=v.y; fcur[4*q+2]=v.z; fcur[4*q+3]=v.w;
        }
        dcur = dws[tid];
    }
    if (tid >= 32 && tid < 48) {
        const int i = tid - 32;
#pragma unroll
        for (int q = 0; q < 4; ++q) {
            float4 v = *(const float4*)&Pws[i * 16 + 4 * q];
            prow[4*q]=v.x; prow[4*q+1]=v.y; prow[4*q+2]=v.z; prow[4*q+3]=v.w;
        }
        pcur = pws[i];
    }
    __syncthreads();
    for (int t = 0; t < T; ++t) {
        // register-prefetch next step's F/d and P/p rows
        float fn[16], dn = 0.f, pn[16], ppn = 0.f;
        if (t < T - 1) {
            if (tid < 16) {
#pragma unroll
                for (int q = 0; q < 4; ++q) {
                    float4 v = *(const float4*)&Fws[(t + 1) * 256 + tid * 16 + 4 * q];
                    fn[4*q]=v.x; fn[4*q+1]=v.y; fn[4*q+2]=v.z; fn[4*q+3]=v.w;
                }
                dn = dws[(t + 1) * 16 + tid];
            }
            if (tid >= 32 && tid < 48) {
                const int i = tid - 32;
#pragma unroll
                for (int q = 0; q < 4; ++q) {
                    float4 v = *(const float4*)&Pws[(t + 1) * 256 + i * 16 + 4 * q];
                    pn[4*q]=v.x; pn[4*q+1]=v.y; pn[4*q+2]=v.z; pn[4*q+3]=v.w;
                }
                ppn = pws[(t + 1) * 16 + i];
            }
        }
        if (tid >= 16 && tid < 24) {        // u_t = -(K_t x_t + k_t)
            const int y = tid - 16;
            float s = dot16f4(&Kall[t][y][0], &z_sh[t][0], kall[t][y]);
            z_sh[t][16 + y] = -s;
        }
        if (tid >= 32 && tid < 48) {        // mu_t = +/- (P_t x_t + p_t)
            const int i = tid - 32;
            float s = pcur;
            const float4* zr = (const float4*)&z_sh[t][0];
#pragma unroll
            for (int q = 0; q < 4; ++q) {
                float4 z = zr[q];
                s = fmaf(prow[4*q+0], z.x, s); s = fmaf(prow[4*q+1], z.y, s);
                s = fmaf(prow[4*q+2], z.z, s); s = fmaf(prow[4*q+3], z.w, s);
            }
            if (t == 0) s = -s;
            out[T * NA + t * 16 + i] = s;
        }
        if (t < T - 1 && tid < 16) {        // x_{t+1} = F_t x_t + d_t
            const float4* zr = (const float4*)&z_sh[t][0];
            float s = dcur;
#pragma unroll
            for (int q = 0; q < 4; ++q) {
                float4 z = zr[q];
                s = fmaf(fcur[4*q+0], z.x, s); s = fmaf(fcur[4*q+1], z.y, s);
                s = fmaf(fcur[4*q+2], z.z, s); s = fmaf(fcur[4*q+3], z.w, s);
            }
            z_sh[t + 1][tid] = s;
        }
        __syncthreads();
        if (t < T - 1) {
            if (tid < 16) {
#pragma unroll
                for (int q = 0; q < 16; ++q) fcur[q] = fn[q];
                dcur = dn;
            }
            if (tid >= 32 && tid < 48) {
#pragma unroll
                for (int q = 0; q < 16; ++q) prow[q] = pn[q];
                pcur = ppn;
            }
        }
    }

    // ---- write z ----
    for (int idx = tid; idx < T * NA; idx += 256)
        out[idx] = z_sh[idx / 24][idx % 24];
}

extern "C" void kernel_launch(void* const* d_in, const int* in_sizes, int n_in,
                              void* d_out, int out_size, void* d_ws, size_t ws_size,
                              hipStream_t stream) {
    const float* gA  = (const float*)d_in[0];
    const float* gB  = (const float*)d_in[1];
    const float* gx0 = (const float*)d_in[2];
    const float* gC  = (const float*)d_in[3];
    const float* gc  = (const float*)d_in[4];
    float* out = (float*)d_out;
    float* Pws = (float*)d_ws;           // T*256 floats
    float* pws = Pws + T * 256;          // T*16
    float* Fws = pws + T * 16;           // T*256
    float* dws = Fws + T * 256;          // T*16   (total 272 KB <= ws_size)
    lqr_solve<<<dim3(1), dim3(256), 0, stream>>>(gA, gB, gx0, gC, gc, out,
                                                 Pws, pws, Fws, dws);
}